// Round 1
// baseline (504.003 us; speedup 1.0000x reference)
//
#include <hip/hip_runtime.h>
#include <hip/hip_bf16.h>

#define NU 200000
#define NI 200000
#define D 128
#define BATCH 4096

typedef __bf16 bf16x8 __attribute__((ext_vector_type(8)));
typedef float f32x4 __attribute__((ext_vector_type(4)));

// ---------------------------------------------------------------------------
// prep: convert pred_W to bf16; build combined cell weights [Wih | Whh | pad]
// (128 x 288) in bf16; sum biases; argmax over batch indices per id
// ---------------------------------------------------------------------------
__global__ __launch_bounds__(256) void prep_kernel(
    const float* __restrict__ predW,
    const float* __restrict__ uWih, const float* __restrict__ uWhh,
    const float* __restrict__ iWih, const float* __restrict__ iWhh,
    const float* __restrict__ ubih, const float* __restrict__ ubhh,
    const float* __restrict__ ibih, const float* __restrict__ ibhh,
    const int* __restrict__ uid, const int* __restrict__ iid,
    __hip_bfloat16* __restrict__ wPred,
    __hip_bfloat16* __restrict__ wU, __hip_bfloat16* __restrict__ wI,
    float* __restrict__ biasU, float* __restrict__ biasI,
    int* __restrict__ lastU, int* __restrict__ lastI)
{
    int idx = blockIdx.x * 256 + threadIdx.x;
    if (idx < 131072) {            // pred_W: 256x512
        wPred[idx] = __float2bfloat16(predW[idx]);
        return;
    }
    idx -= 131072;
    if (idx < 73728) {             // two combined cell weight matrices 128x288
        int z = idx / 36864;
        int r = idx - z * 36864;
        int j = r / 288, k = r - (r / 288) * 288;
        const float* Wih = z ? iWih : uWih;
        const float* Whh = z ? iWhh : uWhh;
        float v = 0.0f;
        if (k < 129)      v = Wih[j * 129 + k];
        else if (k < 257) v = Whh[j * 128 + (k - 129)];
        __hip_bfloat16* W = z ? wI : wU;
        W[j * 288 + k] = __float2bfloat16(v);
        return;
    }
    idx -= 73728;
    if (idx < 128) { biasU[idx] = ubih[idx] + ubhh[idx]; return; }
    idx -= 128;
    if (idx < 128) { biasI[idx] = ibih[idx] + ibhh[idx]; return; }
    idx -= 128;
    if (idx < BATCH) { atomicMax(&lastU[uid[idx]], idx); return; }
    idx -= BATCH;
    if (idx < BATCH) { atomicMax(&lastI[iid[idx]], idx); return; }
}

// ---------------------------------------------------------------------------
// gather: per batch row, build embeddings, write exact fp32 outputs
// (user_emb, item_emb, item_target) and bf16 GEMM operands (xpred, xh_user,
// xh_item).
// ---------------------------------------------------------------------------
__global__ __launch_bounds__(128) void gather_kernel(
    const int* __restrict__ uid, const int* __restrict__ pid,
    const int* __restrict__ iid,
    const float* __restrict__ t_i, const float* __restrict__ t_u,
    const float* __restrict__ dynU, const float* __restrict__ dynI,
    const float* __restrict__ isU, const float* __restrict__ isI,
    const float* __restrict__ statU, const float* __restrict__ statI,
    const float* __restrict__ initU, const float* __restrict__ initI,
    const float* __restrict__ tdW, const float* __restrict__ tdb,
    float* __restrict__ o_user_emb, float* __restrict__ o_item_emb,
    float* __restrict__ o_target,
    __hip_bfloat16* __restrict__ xpred,
    __hip_bfloat16* __restrict__ xhU, __hip_bfloat16* __restrict__ xhI)
{
    int b = blockIdx.x;
    int d = threadIdx.x;
    int u = uid[b], i = iid[b], p = pid[b];
    float fu = isU[u], fi = isI[i], fp = isI[p];
    float iu = initU[d], ii = initI[d];
    float ue = fu * iu + dynU[(size_t)u * D + d];
    float ie = fi * ii + dynI[(size_t)i * D + d];
    float pe = fp * ii + dynI[(size_t)p * D + d];
    float su = statU[(size_t)u * D + d];
    float si = statI[(size_t)i * D + d];
    float sp = statI[(size_t)p * D + d];
    float ti = t_i[b], tu = t_u[b];

    o_user_emb[b * D + d] = ue;
    o_item_emb[b * D + d] = ie;
    o_target[b * 256 + d] = ie;
    o_target[b * 256 + 128 + d] = si;

    float proj = ue * (1.0f + ti * tdW[d] + tdb[d]);

    __hip_bfloat16* xp = xpred + (size_t)b * 512;
    xp[d]       = __float2bfloat16(proj);
    xp[128 + d] = __float2bfloat16(pe);
    xp[256 + d] = __float2bfloat16(sp);
    xp[384 + d] = __float2bfloat16(su);

    __hip_bfloat16* xu = xhU + (size_t)b * 288;
    xu[d]       = __float2bfloat16(ie);
    xu[129 + d] = __float2bfloat16(ue);
    __hip_bfloat16* xi = xhI + (size_t)b * 288;
    xi[d]       = __float2bfloat16(ue);
    xi[129 + d] = __float2bfloat16(ie);
    if (d == 0) {
        xu[128] = __float2bfloat16(ti);
        xi[128] = __float2bfloat16(tu);
    }
    if (d < 31) {
        xu[257 + d] = __float2bfloat16(0.0f);
        xi[257 + d] = __float2bfloat16(0.0f);
    }
}

// ---------------------------------------------------------------------------
// pred GEMM: out = xpred(4096x512) @ pred_W^T(512x256) + pred_b
// 64x64 tile per block, 4 waves, mfma 16x16x32 bf16, direct global loads.
// Verified fragment mapping: A[m=lane&15][k=quad*8+j]; C col=lane&15,
// row=quad*4+reg.
// ---------------------------------------------------------------------------
__global__ __launch_bounds__(256) void gemm_pred(
    const __hip_bfloat16* __restrict__ A,   // 4096 x 512
    const __hip_bfloat16* __restrict__ W,   // 256 x 512
    const float* __restrict__ bias,         // 256
    float* __restrict__ out)                // 4096 x 256
{
    const int K = 512;
    int m0 = blockIdx.x * 64;
    int n0 = blockIdx.y * 64;
    int tid = threadIdx.x;
    int wave = tid >> 6;
    int lane = tid & 63;
    int quad = lane >> 4;
    int l15 = lane & 15;
    int row_a = m0 + wave * 16 + l15;

    f32x4 acc[4] = {};
    const __hip_bfloat16* Arow = A + (size_t)row_a * K;
    for (int k0 = 0; k0 < K; k0 += 32) {
        bf16x8 a = *reinterpret_cast<const bf16x8*>(Arow + k0 + quad * 8);
#pragma unroll
        for (int ct = 0; ct < 4; ++ct) {
            int rw = n0 + ct * 16 + l15;
            bf16x8 bb = *reinterpret_cast<const bf16x8*>(W + (size_t)rw * K + k0 + quad * 8);
            acc[ct] = __builtin_amdgcn_mfma_f32_16x16x32_bf16(a, bb, acc[ct], 0, 0, 0);
        }
    }
    int orow = m0 + wave * 16 + quad * 4;
#pragma unroll
    for (int ct = 0; ct < 4; ++ct) {
        int col = n0 + ct * 16 + l15;
        float bcol = bias[col];
#pragma unroll
        for (int r = 0; r < 4; ++r) {
            out[(size_t)(orow + r) * 256 + col] = acc[ct][r] + bcol;
        }
    }
}

// ---------------------------------------------------------------------------
// cell GEMM: updated = tanh(xh(4096x288) @ Wcomb^T(288x128) + bias)
// z=0: user cell, z=1: item cell. Epilogue writes batch output and the
// last-occurrence-wins scatter into the dynamic embedding output buffer.
// ---------------------------------------------------------------------------
__global__ __launch_bounds__(256) void gemm_cell(
    const __hip_bfloat16* __restrict__ A0, const __hip_bfloat16* __restrict__ A1,
    const __hip_bfloat16* __restrict__ W0, const __hip_bfloat16* __restrict__ W1,
    const float* __restrict__ b0, const float* __restrict__ b1,
    const int* __restrict__ ids0, const int* __restrict__ ids1,
    const int* __restrict__ last0, const int* __restrict__ last1,
    float* __restrict__ outB0, float* __restrict__ outB1,
    float* __restrict__ outD0, float* __restrict__ outD1)
{
    const int K = 288;
    int z = blockIdx.z;
    const __hip_bfloat16* A = z ? A1 : A0;
    const __hip_bfloat16* W = z ? W1 : W0;
    const float* bias = z ? b1 : b0;
    const int* ids  = z ? ids1 : ids0;
    const int* last = z ? last1 : last0;
    float* outB = z ? outB1 : outB0;
    float* outD = z ? outD1 : outD0;

    int m0 = blockIdx.x * 64;
    int n0 = blockIdx.y * 64;
    int tid = threadIdx.x;
    int wave = tid >> 6;
    int lane = tid & 63;
    int quad = lane >> 4;
    int l15 = lane & 15;
    int row_a = m0 + wave * 16 + l15;

    f32x4 acc[4] = {};
    const __hip_bfloat16* Arow = A + (size_t)row_a * K;
    for (int k0 = 0; k0 < K; k0 += 32) {
        bf16x8 a = *reinterpret_cast<const bf16x8*>(Arow + k0 + quad * 8);
#pragma unroll
        for (int ct = 0; ct < 4; ++ct) {
            int rw = n0 + ct * 16 + l15;
            bf16x8 bb = *reinterpret_cast<const bf16x8*>(W + (size_t)rw * K + k0 + quad * 8);
            acc[ct] = __builtin_amdgcn_mfma_f32_16x16x32_bf16(a, bb, acc[ct], 0, 0, 0);
        }
    }
    int orow = m0 + wave * 16 + quad * 4;
#pragma unroll
    for (int ct = 0; ct < 4; ++ct) {
        int col = n0 + ct * 16 + l15;
        float bcol = bias[col];
#pragma unroll
        for (int r = 0; r < 4; ++r) {
            int row = orow + r;
            float v = tanhf(acc[ct][r] + bcol);
            outB[(size_t)row * D + col] = v;
            int id = ids[row];
            if (last[id] == row) {
                outD[(size_t)id * D + col] = v;
            }
        }
    }
}

// ---------------------------------------------------------------------------
// copy: stream dynamic embedding buffers to output, skipping rows owned by
// the cell-GEMM scatter; fused is_*_new copy+zero.
// ---------------------------------------------------------------------------
__global__ __launch_bounds__(256) void copy_kernel(
    const float4* __restrict__ dynU, const float4* __restrict__ dynI,
    const float* __restrict__ isU, const float* __restrict__ isI,
    const int* __restrict__ lastU, const int* __restrict__ lastI,
    float4* __restrict__ oDynU, float4* __restrict__ oDynI,
    float* __restrict__ oIsU, float* __restrict__ oIsI)
{
    long long idx = (long long)blockIdx.x * 256 + threadIdx.x;
    const long long NU4 = (long long)NU * 32;
    const long long NI4 = (long long)NI * 32;
    if (idx < NU4) {
        int row = (int)(idx >> 5);
        if (lastU[row] < 0) oDynU[idx] = dynU[idx];
        return;
    }
    idx -= NU4;
    if (idx < NI4) {
        int row = (int)(idx >> 5);
        if (lastI[row] < 0) oDynI[idx] = dynI[idx];
        return;
    }
    idx -= NI4;
    if (idx < NU) { oIsU[idx] = (lastU[idx] >= 0) ? 0.0f : isU[idx]; return; }
    idx -= NU;
    if (idx < NI) { oIsI[idx] = (lastI[idx] >= 0) ? 0.0f : isI[idx]; return; }
}

// ---------------------------------------------------------------------------
extern "C" void kernel_launch(void* const* d_in, const int* in_sizes, int n_in,
                              void* d_out, int out_size, void* d_ws, size_t ws_size,
                              hipStream_t stream) {
    const int*   uid   = (const int*)d_in[0];
    const int*   pid   = (const int*)d_in[1];
    const int*   iid   = (const int*)d_in[2];
    const float* t_i   = (const float*)d_in[3];
    const float* t_u   = (const float*)d_in[4];
    const float* dynU  = (const float*)d_in[5];
    const float* dynI  = (const float*)d_in[6];
    const float* isU   = (const float*)d_in[7];
    const float* isI   = (const float*)d_in[8];
    const float* statU = (const float*)d_in[9];
    const float* statI = (const float*)d_in[10];
    const float* initU = (const float*)d_in[11];
    const float* initI = (const float*)d_in[12];
    const float* uWih  = (const float*)d_in[13];
    const float* uWhh  = (const float*)d_in[14];
    const float* ubih  = (const float*)d_in[15];
    const float* ubhh  = (const float*)d_in[16];
    const float* iWih  = (const float*)d_in[17];
    const float* iWhh  = (const float*)d_in[18];
    const float* ibih  = (const float*)d_in[19];
    const float* ibhh  = (const float*)d_in[20];
    const float* predW = (const float*)d_in[21];
    const float* predb = (const float*)d_in[22];
    const float* tdW   = (const float*)d_in[23];
    const float* tdb   = (const float*)d_in[24];

    float* out = (float*)d_out;
    float* o_pred     = out;                 // 4096*256
    float* o_target   = out + 1048576;       // 4096*256
    float* o_updU     = out + 2097152;       // 4096*128
    float* o_userEmb  = out + 2621440;       // 4096*128
    float* o_updI     = out + 3145728;       // 4096*128
    float* o_itemEmb  = out + 3670016;       // 4096*128
    float* o_dynU     = out + 4194304;       // 200000*128
    float* o_dynI     = out + 29794304;      // 200000*128
    float* o_isU      = out + 55394304;      // 200000
    float* o_isI      = out + 55594304;      // 200000

    char* ws = (char*)d_ws;
    int* lastU = (int*)ws;                               // NU ints
    int* lastI = lastU + NU;                             // NI ints
    __hip_bfloat16* xpred = (__hip_bfloat16*)(ws + 1600000);     // 4096*512 bf16
    __hip_bfloat16* xhU   = (__hip_bfloat16*)(ws + 5794304);     // 4096*288 bf16
    __hip_bfloat16* xhI   = (__hip_bfloat16*)(ws + 8153600);     // 4096*288 bf16
    __hip_bfloat16* wPred = (__hip_bfloat16*)(ws + 10512896);    // 256*512 bf16
    __hip_bfloat16* wU    = (__hip_bfloat16*)(ws + 10775040);    // 128*288 bf16
    __hip_bfloat16* wI    = (__hip_bfloat16*)(ws + 10848768);    // 128*288 bf16
    float* biasU = (float*)(ws + 10922496);                      // 128 f32
    float* biasI = (float*)(ws + 10923008);                      // 128 f32

    // 1. last-writer arrays := -1
    hipMemsetAsync(lastU, 0xFF, (size_t)(NU + NI) * sizeof(int), stream);

    // 2. weight conversion + argmax
    {
        int total = 131072 + 73728 + 256 + 2 * BATCH;
        int blocks = (total + 255) / 256;
        prep_kernel<<<blocks, 256, 0, stream>>>(
            predW, uWih, uWhh, iWih, iWhh, ubih, ubhh, ibih, ibhh,
            uid, iid, wPred, wU, wI, biasU, biasI, lastU, lastI);
    }

    // 3. gather + operand staging
    gather_kernel<<<BATCH, 128, 0, stream>>>(
        uid, pid, iid, t_i, t_u, dynU, dynI, isU, isI, statU, statI,
        initU, initI, tdW, tdb, o_userEmb, o_itemEmb, o_target,
        xpred, xhU, xhI);

    // 4. prediction head GEMM
    gemm_pred<<<dim3(BATCH / 64, 4), 256, 0, stream>>>(xpred, wPred, predb, o_pred);

    // 5. RNN cell GEMMs (+ scatter of winning rows)
    gemm_cell<<<dim3(BATCH / 64, 2, 2), 256, 0, stream>>>(
        xhU, xhI, wU, wI, biasU, biasI, uid, iid, lastU, lastI,
        o_updU, o_updI, o_dynU, o_dynI);

    // 6. bulk copy of dynamic buffers + is_new flags
    {
        long long total = (long long)NU * 32 + (long long)NI * 32 + NU + NI;
        int blocks = (int)((total + 255) / 256);
        copy_kernel<<<blocks, 256, 0, stream>>>(
            (const float4*)dynU, (const float4*)dynI, isU, isI, lastU, lastI,
            (float4*)o_dynU, (float4*)o_dynI, o_isU, o_isI);
    }
}

// Round 2
// 498.275 us; speedup vs baseline: 1.0115x; 1.0115x over previous
//
#include <hip/hip_runtime.h>
#include <hip/hip_bf16.h>

#define NU 200000
#define NI 200000
#define D 128
#define BATCH 4096

typedef __bf16 bf16x8 __attribute__((ext_vector_type(8)));
typedef float f32x4 __attribute__((ext_vector_type(4)));

__device__ __forceinline__ void store_bf16x4(__hip_bfloat16* p, float4 v) {
    union { __hip_bfloat16 h[4]; uint2 u; } pk;
    pk.h[0] = __float2bfloat16(v.x);
    pk.h[1] = __float2bfloat16(v.y);
    pk.h[2] = __float2bfloat16(v.z);
    pk.h[3] = __float2bfloat16(v.w);
    *reinterpret_cast<uint2*>(p) = pk.u;
}

__device__ __forceinline__ float4 f4_fma(float s, float4 a, float4 b) {
    return make_float4(fmaf(s, a.x, b.x), fmaf(s, a.y, b.y),
                       fmaf(s, a.z, b.z), fmaf(s, a.w, b.w));
}

// ---------------------------------------------------------------------------
// prep: pred_W -> bf16; combined cell weights [Whh | Wih_emb | Wih_t | pad]
// (128 x 288) bf16; bias sums; last-occurrence argmax per id.
// ---------------------------------------------------------------------------
__global__ __launch_bounds__(256) void prep_kernel(
    const float* __restrict__ predW,
    const float* __restrict__ uWih, const float* __restrict__ uWhh,
    const float* __restrict__ iWih, const float* __restrict__ iWhh,
    const float* __restrict__ ubih, const float* __restrict__ ubhh,
    const float* __restrict__ ibih, const float* __restrict__ ibhh,
    const int* __restrict__ uid, const int* __restrict__ iid,
    __hip_bfloat16* __restrict__ wPred,
    __hip_bfloat16* __restrict__ wU, __hip_bfloat16* __restrict__ wI,
    float* __restrict__ biasU, float* __restrict__ biasI,
    int* __restrict__ lastU, int* __restrict__ lastI)
{
    int idx = blockIdx.x * 256 + threadIdx.x;
    if (idx < 131072) {            // pred_W: 256x512
        wPred[idx] = __float2bfloat16(predW[idx]);
        return;
    }
    idx -= 131072;
    if (idx < 73728) {             // two combined cell weight matrices 128x288
        int z = idx / 36864;
        int r = idx - z * 36864;
        int j = r / 288, k = r - (r / 288) * 288;
        const float* Wih = z ? iWih : uWih;
        const float* Whh = z ? iWhh : uWhh;
        float v = 0.0f;
        if (k < 128)      v = Whh[j * 128 + k];          // h part
        else if (k < 257) v = Wih[j * 129 + (k - 128)];  // x part (emb cols + time col)
        __hip_bfloat16* W = z ? wI : wU;
        W[j * 288 + k] = __float2bfloat16(v);
        return;
    }
    idx -= 73728;
    if (idx < 128) { biasU[idx] = ubih[idx] + ubhh[idx]; return; }
    idx -= 128;
    if (idx < 128) { biasI[idx] = ibih[idx] + ibhh[idx]; return; }
    idx -= 128;
    if (idx < BATCH) { atomicMax(&lastU[uid[idx]], idx); return; }
    idx -= BATCH;
    if (idx < BATCH) { atomicMax(&lastI[iid[idx]], idx); return; }
}

// ---------------------------------------------------------------------------
// gather (32 threads/row, float4) + unconditional bulk copies in one grid.
// Gather blocks first so their latency hides under the stream copy.
// xh layout per row (288): [h(0..127) | x_emb(128..255) | t(256) | 0 pad]
// ---------------------------------------------------------------------------
__global__ __launch_bounds__(256) void gather_copy_kernel(
    const int* __restrict__ uid, const int* __restrict__ pid,
    const int* __restrict__ iid,
    const float* __restrict__ t_i, const float* __restrict__ t_u,
    const float* __restrict__ dynU, const float* __restrict__ dynI,
    const float* __restrict__ isU, const float* __restrict__ isI,
    const float* __restrict__ statU, const float* __restrict__ statI,
    const float* __restrict__ initU, const float* __restrict__ initI,
    const float* __restrict__ tdW, const float* __restrict__ tdb,
    float* __restrict__ o_user_emb, float* __restrict__ o_item_emb,
    float* __restrict__ o_target,
    __hip_bfloat16* __restrict__ xpred,
    __hip_bfloat16* __restrict__ xhU, __hip_bfloat16* __restrict__ xhI,
    float4* __restrict__ oDynU, float4* __restrict__ oDynI,
    float4* __restrict__ oIsU, float4* __restrict__ oIsI)
{
    long long idx = (long long)blockIdx.x * 256 + threadIdx.x;
    if (idx < 131072) {                     // gather: 4096 rows x 32 lanes
        int b = (int)(idx >> 5);
        int g = (int)(idx & 31);
        const float4* dU4 = (const float4*)dynU;
        const float4* dI4 = (const float4*)dynI;
        const float4* sU4 = (const float4*)statU;
        const float4* sI4 = (const float4*)statI;

        int u = uid[b], i = iid[b], p = pid[b];
        float fu = isU[u], fi = isI[i], fp = isI[p];
        float ti = t_i[b], tu = t_u[b];

        float4 iu = ((const float4*)initU)[g];
        float4 ii = ((const float4*)initI)[g];
        float4 ue = f4_fma(fu, iu, dU4[(size_t)u * 32 + g]);
        float4 ie = f4_fma(fi, ii, dI4[(size_t)i * 32 + g]);
        float4 pe = f4_fma(fp, ii, dI4[(size_t)p * 32 + g]);
        float4 su = sU4[(size_t)u * 32 + g];
        float4 si = sI4[(size_t)i * 32 + g];
        float4 sp = sI4[(size_t)p * 32 + g];
        float4 tw = ((const float4*)tdW)[g];
        float4 tb = ((const float4*)tdb)[g];

        ((float4*)o_user_emb)[(size_t)b * 32 + g] = ue;
        ((float4*)o_item_emb)[(size_t)b * 32 + g] = ie;
        ((float4*)o_target)[(size_t)b * 64 + g] = ie;
        ((float4*)o_target)[(size_t)b * 64 + 32 + g] = si;

        float4 f = f4_fma(ti, tw, tb);       // ti*tdW + tdb
        float4 proj = make_float4(ue.x * (1.0f + f.x), ue.y * (1.0f + f.y),
                                  ue.z * (1.0f + f.z), ue.w * (1.0f + f.w));

        __hip_bfloat16* xp = xpred + (size_t)b * 512;
        store_bf16x4(xp + 4 * g, proj);
        store_bf16x4(xp + 128 + 4 * g, pe);
        store_bf16x4(xp + 256 + 4 * g, sp);
        store_bf16x4(xp + 384 + 4 * g, su);

        __hip_bfloat16* xu = xhU + (size_t)b * 288;
        store_bf16x4(xu + 4 * g, ue);        // h = user_emb
        store_bf16x4(xu + 128 + 4 * g, ie);  // x = item_emb
        __hip_bfloat16* xi = xhI + (size_t)b * 288;
        store_bf16x4(xi + 4 * g, ie);        // h = item_emb
        store_bf16x4(xi + 128 + 4 * g, ue);  // x = user_emb
        if (g < 8) {                         // cols 256..287: [t, 0...0]
            float4 zu = make_float4(g == 0 ? ti : 0.0f, 0.0f, 0.0f, 0.0f);
            float4 zi = make_float4(g == 0 ? tu : 0.0f, 0.0f, 0.0f, 0.0f);
            store_bf16x4(xu + 256 + 4 * g, zu);
            store_bf16x4(xi + 256 + 4 * g, zi);
        }
        return;
    }
    idx -= 131072;
    if (idx < 6400000) { oDynU[idx] = ((const float4*)dynU)[idx]; return; }
    idx -= 6400000;
    if (idx < 6400000) { oDynI[idx] = ((const float4*)dynI)[idx]; return; }
    idx -= 6400000;
    if (idx < 50000) { oIsU[idx] = ((const float4*)isU)[idx]; return; }
    idx -= 50000;
    if (idx < 50000) { oIsI[idx] = ((const float4*)isI)[idx]; return; }
}

// ---------------------------------------------------------------------------
// fused GEMMs: blocks [0,256) = pred head (4096x512 @ 512x256^T + b),
// blocks [256,512) = two RNN cells (4096x288 @ 288x128^T, tanh) with
// last-occurrence scatter into o_dyn* and is_new zeroing.
// mfma 16x16x32 bf16; A[m=lane&15][k=quad*8+j]; C col=lane&15, row=quad*4+r.
// ---------------------------------------------------------------------------
__global__ __launch_bounds__(256) void gemm_fused(
    const __hip_bfloat16* __restrict__ xpred,
    const __hip_bfloat16* __restrict__ wPred,
    const float* __restrict__ predb, float* __restrict__ o_pred,
    const __hip_bfloat16* __restrict__ xhU, const __hip_bfloat16* __restrict__ xhI,
    const __hip_bfloat16* __restrict__ wU, const __hip_bfloat16* __restrict__ wI,
    const float* __restrict__ biasU, const float* __restrict__ biasI,
    const int* __restrict__ uid, const int* __restrict__ iid,
    const int* __restrict__ lastU, const int* __restrict__ lastI,
    float* __restrict__ o_updU, float* __restrict__ o_updI,
    float* __restrict__ o_dynU, float* __restrict__ o_dynI,
    float* __restrict__ o_isU, float* __restrict__ o_isI)
{
    int bx = blockIdx.x;
    int tid = threadIdx.x;
    int wave = tid >> 6, lane = tid & 63, quad = lane >> 4, l15 = lane & 15;

    if (bx < 256) {
        // ---- prediction head ----
        const int K = 512;
        int m0 = (bx & 63) * 64, n0 = (bx >> 6) * 64;
        f32x4 acc[4] = {};
        const __hip_bfloat16* Arow = xpred + (size_t)(m0 + wave * 16 + l15) * K;
        for (int k0 = 0; k0 < K; k0 += 32) {
            bf16x8 a = *reinterpret_cast<const bf16x8*>(Arow + k0 + quad * 8);
#pragma unroll
            for (int ct = 0; ct < 4; ++ct) {
                bf16x8 b = *reinterpret_cast<const bf16x8*>(
                    wPred + (size_t)(n0 + ct * 16 + l15) * K + k0 + quad * 8);
                acc[ct] = __builtin_amdgcn_mfma_f32_16x16x32_bf16(a, b, acc[ct], 0, 0, 0);
            }
        }
        int orow = m0 + wave * 16 + quad * 4;
#pragma unroll
        for (int ct = 0; ct < 4; ++ct) {
            int col = n0 + ct * 16 + l15;
            float bc = predb[col];
#pragma unroll
            for (int r = 0; r < 4; ++r)
                o_pred[(size_t)(orow + r) * 256 + col] = acc[ct][r] + bc;
        }
    } else {
        // ---- RNN cells ----
        bx -= 256;
        int z = bx >> 7; bx &= 127;
        int m0 = (bx & 63) * 64, n0 = (bx >> 6) * 64;
        const __hip_bfloat16* A = z ? xhI : xhU;
        const __hip_bfloat16* W = z ? wI : wU;
        const float* bias = z ? biasI : biasU;
        const int* ids  = z ? iid : uid;
        const int* last = z ? lastI : lastU;
        float* outB = z ? o_updI : o_updU;
        float* outD = z ? o_dynI : o_dynU;
        float* oIs  = z ? o_isI  : o_isU;

        const int K = 288;
        f32x4 acc[4] = {};
        const __hip_bfloat16* Arow = A + (size_t)(m0 + wave * 16 + l15) * K;
        for (int k0 = 0; k0 < K; k0 += 32) {
            bf16x8 a = *reinterpret_cast<const bf16x8*>(Arow + k0 + quad * 8);
#pragma unroll
            for (int ct = 0; ct < 4; ++ct) {
                bf16x8 b = *reinterpret_cast<const bf16x8*>(
                    W + (size_t)(n0 + ct * 16 + l15) * K + k0 + quad * 8);
                acc[ct] = __builtin_amdgcn_mfma_f32_16x16x32_bf16(a, b, acc[ct], 0, 0, 0);
            }
        }
        int orow = m0 + wave * 16 + quad * 4;
        int rid[4], win[4];
#pragma unroll
        for (int r = 0; r < 4; ++r) {
            int row = orow + r;
            rid[r] = ids[row];
            win[r] = (last[rid[r]] == row);
        }
#pragma unroll
        for (int ct = 0; ct < 4; ++ct) {
            int col = n0 + ct * 16 + l15;
            float bc = bias[col];
#pragma unroll
            for (int r = 0; r < 4; ++r) {
                float v = tanhf(acc[ct][r] + bc);
                outB[(size_t)(orow + r) * D + col] = v;
                if (win[r]) outD[(size_t)rid[r] * D + col] = v;
            }
        }
        if (n0 == 0 && l15 == 0) {
#pragma unroll
            for (int r = 0; r < 4; ++r) oIs[rid[r]] = 0.0f;
        }
    }
}

// ---------------------------------------------------------------------------
extern "C" void kernel_launch(void* const* d_in, const int* in_sizes, int n_in,
                              void* d_out, int out_size, void* d_ws, size_t ws_size,
                              hipStream_t stream) {
    const int*   uid   = (const int*)d_in[0];
    const int*   pid   = (const int*)d_in[1];
    const int*   iid   = (const int*)d_in[2];
    const float* t_i   = (const float*)d_in[3];
    const float* t_u   = (const float*)d_in[4];
    const float* dynU  = (const float*)d_in[5];
    const float* dynI  = (const float*)d_in[6];
    const float* isU   = (const float*)d_in[7];
    const float* isI   = (const float*)d_in[8];
    const float* statU = (const float*)d_in[9];
    const float* statI = (const float*)d_in[10];
    const float* initU = (const float*)d_in[11];
    const float* initI = (const float*)d_in[12];
    const float* uWih  = (const float*)d_in[13];
    const float* uWhh  = (const float*)d_in[14];
    const float* ubih  = (const float*)d_in[15];
    const float* ubhh  = (const float*)d_in[16];
    const float* iWih  = (const float*)d_in[17];
    const float* iWhh  = (const float*)d_in[18];
    const float* ibih  = (const float*)d_in[19];
    const float* ibhh  = (const float*)d_in[20];
    const float* predW = (const float*)d_in[21];
    const float* predb = (const float*)d_in[22];
    const float* tdW   = (const float*)d_in[23];
    const float* tdb   = (const float*)d_in[24];

    float* out = (float*)d_out;
    float* o_pred     = out;                 // 4096*256
    float* o_target   = out + 1048576;       // 4096*256
    float* o_updU     = out + 2097152;       // 4096*128
    float* o_userEmb  = out + 2621440;       // 4096*128
    float* o_updI     = out + 3145728;       // 4096*128
    float* o_itemEmb  = out + 3670016;       // 4096*128
    float* o_dynU     = out + 4194304;       // 200000*128
    float* o_dynI     = out + 29794304;      // 200000*128
    float* o_isU      = out + 55394304;      // 200000
    float* o_isI      = out + 55594304;      // 200000

    char* ws = (char*)d_ws;
    int* lastU = (int*)ws;                               // NU ints
    int* lastI = lastU + NU;                             // NI ints
    __hip_bfloat16* xpred = (__hip_bfloat16*)(ws + 1600000);     // 4096*512 bf16
    __hip_bfloat16* xhU   = (__hip_bfloat16*)(ws + 5794304);     // 4096*288 bf16
    __hip_bfloat16* xhI   = (__hip_bfloat16*)(ws + 8153600);     // 4096*288 bf16
    __hip_bfloat16* wPred = (__hip_bfloat16*)(ws + 10512896);    // 256*512 bf16
    __hip_bfloat16* wU    = (__hip_bfloat16*)(ws + 10775040);    // 128*288 bf16
    __hip_bfloat16* wI    = (__hip_bfloat16*)(ws + 10848768);    // 128*288 bf16
    float* biasU = (float*)(ws + 10922496);                      // 128 f32
    float* biasI = (float*)(ws + 10923008);                      // 128 f32

    // 1. last-writer arrays := -1
    hipMemsetAsync(lastU, 0xFF, (size_t)(NU + NI) * sizeof(int), stream);

    // 2. weight conversion + argmax (213248 threads)
    prep_kernel<<<833, 256, 0, stream>>>(
        predW, uWih, uWhh, iWih, iWhh, ubih, ubhh, ibih, ibhh,
        uid, iid, wPred, wU, wI, biasU, biasI, lastU, lastI);

    // 3. gather + unconditional bulk copies (13,031,072 threads)
    gather_copy_kernel<<<50903, 256, 0, stream>>>(
        uid, pid, iid, t_i, t_u, dynU, dynI, isU, isI, statU, statI,
        initU, initI, tdW, tdb, o_userEmb, o_itemEmb, o_target,
        xpred, xhU, xhI,
        (float4*)o_dynU, (float4*)o_dynI, (float4*)o_isU, (float4*)o_isI);

    // 4. fused GEMMs + scatter + is_new zeroing
    gemm_fused<<<512, 256, 0, stream>>>(
        xpred, wPred, predb, o_pred,
        xhU, xhI, wU, wI, biasU, biasI,
        uid, iid, lastU, lastI,
        o_updU, o_updI, o_dynU, o_dynI, o_isU, o_isI);
}